// Round 18
// baseline (128.713 us; speedup 1.0000x reference)
//
#include <hip/hip_runtime.h>
#include <stdint.h>

#define NPRED 2048
#define MT    512
#define BLK   256
#define NCAND 512

template<int C>
__device__ __forceinline__ uint32_t dppminu(uint32_t v) {
  uint32_t o = (uint32_t)__builtin_amdgcn_update_dpp((int)v, (int)v, C, 0xF, 0xF, false);
  return v < o ? v : o;
}
__device__ __forceinline__ uint32_t wave_min_u32_l63(uint32_t v) {
  v = dppminu<0x111>(v); v = dppminu<0x112>(v); v = dppminu<0x114>(v);
  v = dppminu<0x118>(v); v = dppminu<0x142>(v); v = dppminu<0x143>(v);
  return (uint32_t)__builtin_amdgcn_readlane((int)v, 63);
}
__device__ __forceinline__ uint32_t rowmin16(uint32_t v) {  // lanes 15/31/47/63 hold row min
  v = dppminu<0x111>(v); v = dppminu<0x112>(v);
  v = dppminu<0x114>(v); v = dppminu<0x118>(v);
  return v;
}
__device__ __forceinline__ float wave_sum_f32(float v) {
#pragma unroll
  for (int off = 32; off; off >>= 1) v += __shfl_xor(v, off, 64);
  return v;
}

__global__ __launch_bounds__(BLK, 1) void loss_kernel(const float* __restrict__ preds,
                                                      const float* __restrict__ targets,
                                                      double* __restrict__ acc) {
  const int b = blockIdx.x;
  const float* __restrict__ P = preds   + (size_t)b * NPRED * 5;
  const float* __restrict__ T = targets + (size_t)b * MT * 5;

  __shared__ uint64_t cand[NCAND];                     // 4 KB
  __shared__ float txy[MT * 2];                        // 4 KB (tx,ty interleaved)
  __shared__ float tab[MT * 2];                        // 4 KB (ta,tb interleaved)
  __shared__ float spx[520], spy[520], spa[520], spb[520]; // 8.3 KB
  __shared__ uint16_t plds[512];                       // 1 KB
  __shared__ int hist[256];                            // 1 KB
  __shared__ uint32_t validw[16];
  __shared__ int s_npos, s_nt, s_B, s_ncand, s_first;
  __shared__ uint64_t s_thr;

  const int tid = threadIdx.x;
  if (tid == 0) { s_npos = 0; s_nt = 0; s_B = 0; s_ncand = 0; s_first = 0; s_thr = 0ull; }
  hist[tid] = 0;
  if (tid < 16) validw[tid] = 0;
  // zero-pad sp arrays (pads [n_targs,520) must read as 0)
  for (int i = tid; i < 520; i += BLK) { spx[i] = 0.f; spy[i] = 0.f; spa[i] = 0.f; spb[i] = 0.f; }
  __syncthreads();

  // ---- conf histogram + n_pos ----
  int cpos = 0;
  for (int i = tid; i < NPRED; i += BLK) {
    float c = P[i * 5 + 0];
    cpos += (c > 0.5f) ? 1 : 0;
    uint32_t cb = __float_as_uint(c);
    if (cb >= 0x3F000000u && cb < 0x3F800000u)
      atomicAdd(&hist[(cb >> 15) & 0xFF], 1);
  }
  atomicAdd(&s_npos, cpos);

  // ---- stage targets + validity + n_targs ----
  int ct = 0;
  for (int m = tid; m < MT; m += BLK) {
    float tp = T[m * 5 + 0];
    bool v = (tp == 1.0f);
    if (v) { ct++; atomicOr(&validw[m >> 5], 1u << (m & 31)); }
    txy[2 * m]     = T[m * 5 + 1];
    txy[2 * m + 1] = T[m * 5 + 2];
    tab[2 * m]     = T[m * 5 + 3];
    tab[2 * m + 1] = T[m * 5 + 4];
  }
  atomicAdd(&s_nt, ct);
  __syncthreads();
  const int n_pos = s_npos;
  const int n_targs = s_nt;

  // ---- wave0: suffix-scan histogram -> cutoff bucket B ----
  if (tid < 64) {
    const int lane = tid;
    int4 h4 = *reinterpret_cast<const int4*>(&hist[lane * 4]);
    int t = h4.x + h4.y + h4.z + h4.w;
    int S = t;
#pragma unroll
    for (int off = 1; off < 64; off <<= 1) {
      int o = __shfl_down(S, off);
      if (lane + off < 64) S += o;
    }
    int Snext = S - t;
    int s3 = h4.w + Snext;
    int s2 = h4.z + s3;
    int s1 = h4.y + s2;
    int s0 = h4.x + s1;
    int localB = -1;
    if      (s3 >= n_targs) localB = lane * 4 + 3;
    else if (s2 >= n_targs) localB = lane * 4 + 2;
    else if (s1 >= n_targs) localB = lane * 4 + 1;
    else if (s0 >= n_targs) localB = lane * 4 + 0;
    uint64_t q = __ballot(localB >= 0);
    if (q) {
      int hl = 63 - __clzll((long long)q);
      int B = __builtin_amdgcn_readlane(localB, hl);
      if (lane == 0) s_B = B;
    }
  }
  __syncthreads();
  const int B = s_B;

  // ---- gather candidates (bucket >= B); keys built on the fly ----
  for (int i = tid; i < NPRED; i += BLK) {
    uint32_t cb = __float_as_uint(P[i * 5 + 0]);
    if (cb >= 0x3F000000u && cb < 0x3F800000u && (int)((cb >> 15) & 0xFF) >= B) {
      int slot = atomicAdd(&s_ncand, 1);
      if (slot < NCAND) cand[slot] = ((uint64_t)(~cb) << 32) | (uint32_t)i;
    }
  }
  __syncthreads();
  const int ncand = min(s_ncand, NCAND);

  // ---- rank-sort: scatter pred rows into sp* by rank; thrkey at rank n_targs-1 ----
  {
    uint64_t ka = (tid < ncand) ? cand[tid] : ~0ull;
    uint64_t kb = (tid + BLK < ncand) ? cand[tid + BLK] : ~0ull;
    int ra = 0, rb = 0;
    for (int j = 0; j < ncand; ++j) {
      uint64_t kj = cand[j];
      ra += (kj < ka) ? 1 : 0;
      rb += (kj < kb) ? 1 : 0;
    }
    if (tid < ncand && ra < n_targs) {
      int idx = (int)(ka & 0xFFFFFFFFu);
      spx[ra] = P[idx * 5 + 1]; spy[ra] = P[idx * 5 + 2];
      spa[ra] = P[idx * 5 + 3]; spb[ra] = P[idx * 5 + 4];
    }
    if (tid < ncand && ra == n_targs - 1) s_thr = ka;
    if (tid + BLK < ncand && rb < n_targs) {
      int idx = (int)(kb & 0xFFFFFFFFu);
      spx[rb] = P[idx * 5 + 1]; spy[rb] = P[idx * 5 + 2];
      spa[rb] = P[idx * 5 + 3]; spb[rb] = P[idx * 5 + 4];
    }
    if (tid + BLK < ncand && rb == n_targs - 1) s_thr = kb;
  }
  __syncthreads();
  const uint64_t thr = s_thr;
  const int K = min(n_pos, n_targs);

  float accp = 0.f;

  if (tid < 64) {
    // ---- wave0: 4-pred group-split greedy match (R14 codegen, frozen) ----
    const int lane = tid;
    const int s = lane & 15;     // target-word index (targets s*32 .. s*32+31)
    const int g = lane >> 4;     // group 0..3 -> pred i+g
    const uint32_t sbase = (uint32_t)(s << 5);

    float txr[32], tyr[32];
#pragma unroll
    for (int j = 0; j < 32; ++j) {
      txr[j] = txy[2 * (s * 32 + j)];
      tyr[j] = txy[2 * (s * 32 + j) + 1];
    }
    uint32_t una = ~validw[s];   // 1 = invalid-or-used

    int i = 0;
    float x = spx[g], y = spy[g];
    while (i + 4 <= K) {
      // prefetch all 4 possible next positions for this group (latency hidden)
      float nx1 = spx[i + 1 + g], ny1 = spy[i + 1 + g];
      float nx2 = spx[i + 2 + g], ny2 = spy[i + 2 + g];
      float nx3 = spx[i + 3 + g], ny3 = spy[i + 3 + g];
      float nx4 = spx[i + 4 + g], ny4 = spy[i + 4 + g];

      // two independent min accumulators over local-j keys
      uint32_t ke = 0xFFFFFFFFu, ko = 0xFFFFFFFFu;
#pragma unroll
      for (int j = 0; j < 32; j += 2) {
        {
          float dx = __fsub_rn(txr[j], x);
          float dy = __fsub_rn(tyr[j], y);
          float d2 = __fadd_rn(__fmul_rn(dx, dx), __fmul_rn(dy, dy));
          uint32_t pois = (uint32_t)(((int32_t)(una << (31 - j))) >> 31);
          uint32_t key = ((__float_as_uint(d2) | pois) & 0xFFFFFE00u) | (uint32_t)j;
          ke = ke < key ? ke : key;
        }
        {
          float dx = __fsub_rn(txr[j + 1], x);
          float dy = __fsub_rn(tyr[j + 1], y);
          float d2 = __fadd_rn(__fmul_rn(dx, dx), __fmul_rn(dy, dy));
          uint32_t pois = (uint32_t)(((int32_t)(una << (31 - (j + 1)))) >> 31);
          uint32_t key = ((__float_as_uint(d2) | pois) & 0xFFFFFE00u) | (uint32_t)(j + 1);
          ko = ko < key ? ko : key;
        }
      }
      uint32_t kk = ke < ko ? ke : ko;
      uint32_t kkg = rowmin16(kk + sbase);   // low 9 bits -> global target idx (carry-free)
      int m0 = __builtin_amdgcn_readlane((int)kkg, 15) & 0x1FF;
      int m1 = __builtin_amdgcn_readlane((int)kkg, 31) & 0x1FF;
      int m2 = __builtin_amdgcn_readlane((int)kkg, 47) & 0x1FF;
      int m3 = __builtin_amdgcn_readlane((int)kkg, 63) & 0x1FF;

      // branchless distinct-prefix length p
      int p = (m1 == m0) ? 1
            : (m2 == m0 || m2 == m1) ? 2
            : (m3 == m0 || m3 == m1 || m3 == m2) ? 3 : 4;
      int m1e = (p > 1) ? m1 : 0x3FF;   // 0x3FF decodes to word 31 != any s<16
      int m2e = (p > 2) ? m2 : 0x3FF;
      int m3e = (p > 3) ? m3 : 0x3FF;

      // commit: poison hit targets in this lane's word
      una |= ((uint32_t)(m0  >> 5) == (uint32_t)s) ? (1u << (m0  & 31)) : 0u;
      una |= ((uint32_t)(m1e >> 5) == (uint32_t)s) ? (1u << (m1e & 31)) : 0u;
      una |= ((uint32_t)(m2e >> 5) == (uint32_t)s) ? (1u << (m2e & 31)) : 0u;
      una |= ((uint32_t)(m3e >> 5) == (uint32_t)s) ? (1u << (m3e & 31)) : 0u;

      if (lane == 0) {
        plds[i]     = (uint16_t)m0;
        plds[i + 1] = (uint16_t)m1e;   // garbage slots overwritten by later iters/tail
        plds[i + 2] = (uint16_t)m2e;
        plds[i + 3] = (uint16_t)m3e;
      }
      i += p;
      x = (p == 1) ? nx1 : (p == 2) ? nx2 : (p == 3) ? nx3 : nx4;
      y = (p == 1) ? ny1 : (p == 2) ? ny2 : (p == 3) ? ny3 : ny4;
    }
    // tail: single-pred steps (row 0 covers all 512 targets)
    while (i < K) {
      float xs = spx[i], ys = spy[i];
      uint32_t ke = 0xFFFFFFFFu, ko = 0xFFFFFFFFu;
#pragma unroll
      for (int j = 0; j < 32; j += 2) {
        {
          float dx = __fsub_rn(txr[j], xs);
          float dy = __fsub_rn(tyr[j], ys);
          float d2 = __fadd_rn(__fmul_rn(dx, dx), __fmul_rn(dy, dy));
          uint32_t pois = (uint32_t)(((int32_t)(una << (31 - j))) >> 31);
          uint32_t key = ((__float_as_uint(d2) | pois) & 0xFFFFFE00u) | (uint32_t)j;
          ke = ke < key ? ke : key;
        }
        {
          float dx = __fsub_rn(txr[j + 1], xs);
          float dy = __fsub_rn(tyr[j + 1], ys);
          float d2 = __fadd_rn(__fmul_rn(dx, dx), __fmul_rn(dy, dy));
          uint32_t pois = (uint32_t)(((int32_t)(una << (31 - (j + 1)))) >> 31);
          uint32_t key = ((__float_as_uint(d2) | pois) & 0xFFFFFE00u) | (uint32_t)(j + 1);
          ko = ko < key ? ko : key;
        }
      }
      uint32_t kk = ke < ko ? ke : ko;
      uint32_t kkg = rowmin16(kk + sbase);
      uint32_t m = (uint32_t)__builtin_amdgcn_readlane((int)kkg, 15) & 0x1FFu;
      una |= ((m >> 5) == (uint32_t)s) ? (1u << (m & 31u)) : 0u;
      if (lane == 0) plds[i] = (uint16_t)m;
      ++i;
    }
    // first valid unused target
    uint32_t av = ~una;
    uint32_t fi = av ? (sbase + (uint32_t)__ffs(av) - 1u) : 0xFFFFFFFFu;
    fi = wave_min_u32_l63(fi);
    if (lane == 0) s_first = (fi < MT) ? (int)fi : 0;
  } else {
    // ---- waves 1-3: prob loss (t = on-the-fly key <= thrkey) ----
    for (int i = tid - 64; i < NPRED; i += (BLK - 64)) {
      float p = P[i * 5 + 0];
      uint32_t cb = __float_as_uint(p);
      uint64_t k = ((uint64_t)(~cb) << 32) | (uint32_t)i;
      accp += (k <= thr) ? -fmaxf(logf(p), -100.0f)
                         : -fmaxf(log1pf(-p), -100.0f);
    }
  }
  __syncthreads();

  // ---- fused MSE over matched pairs + case_first ----
  float ax = 0.f, ay = 0.f, aa = 0.f, ab = 0.f;
  for (int r = tid; r < K; r += BLK) {
    int m = plds[r];
    float dx = __fsub_rn(spx[r], txy[2 * m]);
    float dy = __fsub_rn(spy[r], txy[2 * m + 1]);
    float da = __fsub_rn(spa[r], tab[2 * m]);
    float db = __fsub_rn(spb[r], tab[2 * m + 1]);
    ax += __fmul_rn(dx, dx);
    ay += __fmul_rn(dy, dy);
    aa += __fmul_rn(da, da);
    ab += __fmul_rn(db, db);
  }
  if (n_pos < n_targs) {
    int f = s_first;
    float fx = txy[2 * f], fy = txy[2 * f + 1];
    float fa = tab[2 * f], fb = tab[2 * f + 1];
    for (int i2 = n_pos + tid; i2 < n_targs; i2 += BLK) {
      float dx = __fsub_rn(spx[i2], fx);
      float dy = __fsub_rn(spy[i2], fy);
      float da = __fsub_rn(spa[i2], fa);
      float db = __fsub_rn(spb[i2], fb);
      ax += __fmul_rn(dx, dx);
      ay += __fmul_rn(dy, dy);
      aa += __fmul_rn(da, da);
      ab += __fmul_rn(db, db);
    }
  }

  // ---- wave reduce + per-wave f64 atomics (no barriers) ----
  ax = wave_sum_f32(ax);
  ay = wave_sum_f32(ay);
  aa = wave_sum_f32(aa);
  ab = wave_sum_f32(ab);
  accp = wave_sum_f32(accp);
  if ((tid & 63) == 0) {
    atomicAdd(&acc[0], (double)ax);
    atomicAdd(&acc[1], (double)ay);
    atomicAdd(&acc[2], (double)aa);
    atomicAdd(&acc[3], (double)ab);
    atomicAdd(&acc[4], (double)accp);
  }
}

__global__ void finalize_kernel(const double* __restrict__ acc,
                                float* __restrict__ out, double inv) {
  int c = threadIdx.x;
  if (c < 5) out[c] = (float)(acc[c] * inv);
}

extern "C" void kernel_launch(void* const* d_in, const int* in_sizes, int n_in,
                              void* d_out, int out_size, void* d_ws, size_t ws_size,
                              hipStream_t stream) {
  const float* preds = (const float*)d_in[0];
  const float* targets = (const float*)d_in[1];
  int B = in_sizes[0] / (NPRED * 5);

  double* acc = (double*)d_ws;
  hipMemsetAsync(acc, 0, 5 * sizeof(double), stream);
  loss_kernel<<<B, BLK, 0, stream>>>(preds, targets, acc);
  finalize_kernel<<<1, 64, 0, stream>>>(acc, (float*)d_out,
                                        1.0 / ((double)B * NPRED));
}

// Round 19
// 84.040 us; speedup vs baseline: 1.5316x; 1.5316x over previous
//
#include <hip/hip_runtime.h>
#include <stdint.h>

#define NPRED 2048
#define MT    512
#define BLK   256
#define NCAND 512

template<int C>
__device__ __forceinline__ uint32_t dppminu(uint32_t v) {
  uint32_t o = (uint32_t)__builtin_amdgcn_update_dpp((int)v, (int)v, C, 0xF, 0xF, false);
  return v < o ? v : o;
}
__device__ __forceinline__ uint32_t wave_min_u32_l63(uint32_t v) {
  v = dppminu<0x111>(v); v = dppminu<0x112>(v); v = dppminu<0x114>(v);
  v = dppminu<0x118>(v); v = dppminu<0x142>(v); v = dppminu<0x143>(v);
  return (uint32_t)__builtin_amdgcn_readlane((int)v, 63);
}
__device__ __forceinline__ uint32_t rowmin16(uint32_t v) {  // lanes 15/31/47/63 hold row min
  v = dppminu<0x111>(v); v = dppminu<0x112>(v);
  v = dppminu<0x114>(v); v = dppminu<0x118>(v);
  return v;
}

__global__ __launch_bounds__(BLK, 1) void loss_kernel(const float* __restrict__ preds,
                                                      const float* __restrict__ targets,
                                                      double* __restrict__ acc) {
  const int b = blockIdx.x;
  const float* __restrict__ P = preds   + (size_t)b * NPRED * 5;
  const float* __restrict__ T = targets + (size_t)b * MT * 5;

  __shared__ uint64_t keys[NPRED];                     // 16 KB
  __shared__ uint64_t cand[NCAND];                     // 4 KB
  __shared__ float txy[MT * 2];                        // 4 KB (tx,ty interleaved)
  __shared__ float tab[MT * 2];                        // 4 KB (ta,tb interleaved)
  __shared__ float spx[520], spy[520], spa[520], spb[520]; // 8.3 KB
  __shared__ uint16_t plds[512];                       // 1 KB
  __shared__ int hist[256];                            // 1 KB
  __shared__ uint32_t validw[16];
  __shared__ int s_npos, s_nt, s_B, s_ncand, s_first;
  __shared__ uint64_t s_thr;
  __shared__ double red[5][BLK];                       // 10 KB

  const int tid = threadIdx.x;
  if (tid == 0) { s_npos = 0; s_nt = 0; s_B = 0; s_ncand = 0; s_first = 0; s_thr = 0ull; }
  hist[tid] = 0;
  if (tid < 16) validw[tid] = 0;
  // zero-pad sp arrays (pads [n_targs,520) must read as 0)
  for (int i = tid; i < 520; i += BLK) { spx[i] = 0.f; spy[i] = 0.f; spa[i] = 0.f; spb[i] = 0.f; }
  __syncthreads();

  // ---- keys + histogram of conf in [0.5,1) + n_pos ----
  int cpos = 0;
  for (int i = tid; i < NPRED; i += BLK) {
    float c = P[i * 5 + 0];
    cpos += (c > 0.5f) ? 1 : 0;
    uint32_t cb = __float_as_uint(c);
    keys[i] = ((uint64_t)(~cb) << 32) | (uint32_t)i;   // asc key == conf desc, idx asc
    if (cb >= 0x3F000000u && cb < 0x3F800000u)
      atomicAdd(&hist[(cb >> 15) & 0xFF], 1);
  }
  atomicAdd(&s_npos, cpos);

  // ---- stage targets + validity + n_targs ----
  int ct = 0;
  for (int m = tid; m < MT; m += BLK) {
    float tp = T[m * 5 + 0];
    bool v = (tp == 1.0f);
    if (v) { ct++; atomicOr(&validw[m >> 5], 1u << (m & 31)); }
    txy[2 * m]     = T[m * 5 + 1];
    txy[2 * m + 1] = T[m * 5 + 2];
    tab[2 * m]     = T[m * 5 + 3];
    tab[2 * m + 1] = T[m * 5 + 4];
  }
  atomicAdd(&s_nt, ct);
  __syncthreads();
  const int n_pos = s_npos;
  const int n_targs = s_nt;

  // ---- wave0: suffix-scan histogram -> cutoff bucket B ----
  if (tid < 64) {
    const int lane = tid;
    int4 h4 = *reinterpret_cast<const int4*>(&hist[lane * 4]);
    int t = h4.x + h4.y + h4.z + h4.w;
    int S = t;
#pragma unroll
    for (int off = 1; off < 64; off <<= 1) {
      int o = __shfl_down(S, off);
      if (lane + off < 64) S += o;
    }
    int Snext = S - t;
    int s3 = h4.w + Snext;
    int s2 = h4.z + s3;
    int s1 = h4.y + s2;
    int s0 = h4.x + s1;
    int localB = -1;
    if      (s3 >= n_targs) localB = lane * 4 + 3;
    else if (s2 >= n_targs) localB = lane * 4 + 2;
    else if (s1 >= n_targs) localB = lane * 4 + 1;
    else if (s0 >= n_targs) localB = lane * 4 + 0;
    uint64_t q = __ballot(localB >= 0);
    if (q) {
      int hl = 63 - __clzll((long long)q);
      int B = __builtin_amdgcn_readlane(localB, hl);
      if (lane == 0) s_B = B;
    }
  }
  __syncthreads();
  const int B = s_B;

  // ---- gather candidates (bucket >= B) ----
  for (int i = tid; i < NPRED; i += BLK) {
    uint64_t k = keys[i];
    uint32_t cb = ~(uint32_t)(k >> 32);
    if (cb >= 0x3F000000u && cb < 0x3F800000u && (int)((cb >> 15) & 0xFF) >= B) {
      int slot = atomicAdd(&s_ncand, 1);
      if (slot < NCAND) cand[slot] = k;
    }
  }
  __syncthreads();
  const int ncand = min(s_ncand, NCAND);

  // ---- rank-sort: scatter pred rows into sp* by rank; thrkey at rank n_targs-1 ----
  {
    uint64_t ka = (tid < ncand) ? cand[tid] : ~0ull;
    uint64_t kb = (tid + BLK < ncand) ? cand[tid + BLK] : ~0ull;
    int ra = 0, rb = 0;
    for (int j = 0; j < ncand; ++j) {
      uint64_t kj = cand[j];
      ra += (kj < ka) ? 1 : 0;
      rb += (kj < kb) ? 1 : 0;
    }
    if (tid < ncand && ra < n_targs) {
      int idx = (int)(ka & 0xFFFFFFFFu);
      spx[ra] = P[idx * 5 + 1]; spy[ra] = P[idx * 5 + 2];
      spa[ra] = P[idx * 5 + 3]; spb[ra] = P[idx * 5 + 4];
    }
    if (tid < ncand && ra == n_targs - 1) s_thr = ka;
    if (tid + BLK < ncand && rb < n_targs) {
      int idx = (int)(kb & 0xFFFFFFFFu);
      spx[rb] = P[idx * 5 + 1]; spy[rb] = P[idx * 5 + 2];
      spa[rb] = P[idx * 5 + 3]; spb[rb] = P[idx * 5 + 4];
    }
    if (tid + BLK < ncand && rb == n_targs - 1) s_thr = kb;
  }
  __syncthreads();
  const uint64_t thr = s_thr;
  const int K = min(n_pos, n_targs);

  float accp = 0.f;

  if (tid < 64) {
    // ---- wave0: 4-pred group-split greedy match (local-j keys, dual min acc) ----
    const int lane = tid;
    const int s = lane & 15;     // target-word index (targets s*32 .. s*32+31)
    const int g = lane >> 4;     // group 0..3 -> pred i+g
    const uint32_t sbase = (uint32_t)(s << 5);

    float txr[32], tyr[32];
#pragma unroll
    for (int j = 0; j < 32; ++j) {
      txr[j] = txy[2 * (s * 32 + j)];
      tyr[j] = txy[2 * (s * 32 + j) + 1];
    }
    uint32_t una = ~validw[s];   // 1 = invalid-or-used

    int i = 0;
    float x = spx[g], y = spy[g];
    while (i + 4 <= K) {
      // prefetch all 4 possible next positions for this group (latency hidden)
      float nx1 = spx[i + 1 + g], ny1 = spy[i + 1 + g];
      float nx2 = spx[i + 2 + g], ny2 = spy[i + 2 + g];
      float nx3 = spx[i + 3 + g], ny3 = spy[i + 3 + g];
      float nx4 = spx[i + 4 + g], ny4 = spy[i + 4 + g];

      // two independent min accumulators over local-j keys
      uint32_t ke = 0xFFFFFFFFu, ko = 0xFFFFFFFFu;
#pragma unroll
      for (int j = 0; j < 32; j += 2) {
        {
          float dx = __fsub_rn(txr[j], x);
          float dy = __fsub_rn(tyr[j], y);
          float d2 = __fadd_rn(__fmul_rn(dx, dx), __fmul_rn(dy, dy));
          uint32_t pois = (uint32_t)(((int32_t)(una << (31 - j))) >> 31);
          uint32_t key = ((__float_as_uint(d2) | pois) & 0xFFFFFE00u) | (uint32_t)j;
          ke = ke < key ? ke : key;
        }
        {
          float dx = __fsub_rn(txr[j + 1], x);
          float dy = __fsub_rn(tyr[j + 1], y);
          float d2 = __fadd_rn(__fmul_rn(dx, dx), __fmul_rn(dy, dy));
          uint32_t pois = (uint32_t)(((int32_t)(una << (31 - (j + 1)))) >> 31);
          uint32_t key = ((__float_as_uint(d2) | pois) & 0xFFFFFE00u) | (uint32_t)(j + 1);
          ko = ko < key ? ko : key;
        }
      }
      uint32_t kk = ke < ko ? ke : ko;
      uint32_t kkg = rowmin16(kk + sbase);   // low 9 bits -> global target idx (carry-free)
      int m0 = __builtin_amdgcn_readlane((int)kkg, 15) & 0x1FF;
      int m1 = __builtin_amdgcn_readlane((int)kkg, 31) & 0x1FF;
      int m2 = __builtin_amdgcn_readlane((int)kkg, 47) & 0x1FF;
      int m3 = __builtin_amdgcn_readlane((int)kkg, 63) & 0x1FF;

      // branchless distinct-prefix length p
      int p = (m1 == m0) ? 1
            : (m2 == m0 || m2 == m1) ? 2
            : (m3 == m0 || m3 == m1 || m3 == m2) ? 3 : 4;
      int m1e = (p > 1) ? m1 : 0x3FF;   // 0x3FF decodes to word 31 != any s<16
      int m2e = (p > 2) ? m2 : 0x3FF;
      int m3e = (p > 3) ? m3 : 0x3FF;

      // commit: poison hit targets in this lane's word
      una |= ((uint32_t)(m0  >> 5) == (uint32_t)s) ? (1u << (m0  & 31)) : 0u;
      una |= ((uint32_t)(m1e >> 5) == (uint32_t)s) ? (1u << (m1e & 31)) : 0u;
      una |= ((uint32_t)(m2e >> 5) == (uint32_t)s) ? (1u << (m2e & 31)) : 0u;
      una |= ((uint32_t)(m3e >> 5) == (uint32_t)s) ? (1u << (m3e & 31)) : 0u;

      if (lane == 0) {
        plds[i]     = (uint16_t)m0;
        plds[i + 1] = (uint16_t)m1e;   // garbage slots overwritten by later iters/tail
        plds[i + 2] = (uint16_t)m2e;
        plds[i + 3] = (uint16_t)m3e;
      }
      i += p;
      x = (p == 1) ? nx1 : (p == 2) ? nx2 : (p == 3) ? nx3 : nx4;
      y = (p == 1) ? ny1 : (p == 2) ? ny2 : (p == 3) ? ny3 : ny4;
    }
    // tail: single-pred steps (row 0 covers all 512 targets)
    while (i < K) {
      float xs = spx[i], ys = spy[i];
      uint32_t ke = 0xFFFFFFFFu, ko = 0xFFFFFFFFu;
#pragma unroll
      for (int j = 0; j < 32; j += 2) {
        {
          float dx = __fsub_rn(txr[j], xs);
          float dy = __fsub_rn(tyr[j], ys);
          float d2 = __fadd_rn(__fmul_rn(dx, dx), __fmul_rn(dy, dy));
          uint32_t pois = (uint32_t)(((int32_t)(una << (31 - j))) >> 31);
          uint32_t key = ((__float_as_uint(d2) | pois) & 0xFFFFFE00u) | (uint32_t)j;
          ke = ke < key ? ke : key;
        }
        {
          float dx = __fsub_rn(txr[j + 1], xs);
          float dy = __fsub_rn(tyr[j + 1], ys);
          float d2 = __fadd_rn(__fmul_rn(dx, dx), __fmul_rn(dy, dy));
          uint32_t pois = (uint32_t)(((int32_t)(una << (31 - (j + 1)))) >> 31);
          uint32_t key = ((__float_as_uint(d2) | pois) & 0xFFFFFE00u) | (uint32_t)(j + 1);
          ko = ko < key ? ko : key;
        }
      }
      uint32_t kk = ke < ko ? ke : ko;
      uint32_t kkg = rowmin16(kk + sbase);
      uint32_t m = (uint32_t)__builtin_amdgcn_readlane((int)kkg, 15) & 0x1FFu;
      una |= ((m >> 5) == (uint32_t)s) ? (1u << (m & 31u)) : 0u;
      if (lane == 0) plds[i] = (uint16_t)m;
      ++i;
    }
    // first valid unused target
    uint32_t av = ~una;
    uint32_t fi = av ? (sbase + (uint32_t)__ffs(av) - 1u) : 0xFFFFFFFFu;
    fi = wave_min_u32_l63(fi);
    if (lane == 0) s_first = (fi < MT) ? (int)fi : 0;
  } else {
    // ---- waves 1-3: prob loss (t = key <= thrkey) ----
    for (int i = tid - 64; i < NPRED; i += (BLK - 64)) {
      uint64_t k = keys[i];
      float p = __uint_as_float(~(uint32_t)(k >> 32));
      accp += (k <= thr) ? -fmaxf(logf(p), -100.0f)
                         : -fmaxf(log1pf(-p), -100.0f);
    }
  }
  __syncthreads();

  // ---- fused MSE over matched pairs + case_first ----
  float ax = 0.f, ay = 0.f, aa = 0.f, ab = 0.f;
  for (int r = tid; r < K; r += BLK) {
    int m = plds[r];
    float dx = __fsub_rn(spx[r], txy[2 * m]);
    float dy = __fsub_rn(spy[r], txy[2 * m + 1]);
    float da = __fsub_rn(spa[r], tab[2 * m]);
    float db = __fsub_rn(spb[r], tab[2 * m + 1]);
    ax += __fmul_rn(dx, dx);
    ay += __fmul_rn(dy, dy);
    aa += __fmul_rn(da, da);
    ab += __fmul_rn(db, db);
  }
  if (n_pos < n_targs) {
    int f = s_first;
    float fx = txy[2 * f], fy = txy[2 * f + 1];
    float fa = tab[2 * f], fb = tab[2 * f + 1];
    for (int i2 = n_pos + tid; i2 < n_targs; i2 += BLK) {
      float dx = __fsub_rn(spx[i2], fx);
      float dy = __fsub_rn(spy[i2], fy);
      float da = __fsub_rn(spa[i2], fa);
      float db = __fsub_rn(spb[i2], fb);
      ax += __fmul_rn(dx, dx);
      ay += __fmul_rn(dy, dy);
      aa += __fmul_rn(da, da);
      ab += __fmul_rn(db, db);
    }
  }

  // ---- block reduce (doubles) + global atomic ----
  red[0][tid] = (double)ax;
  red[1][tid] = (double)ay;
  red[2][tid] = (double)aa;
  red[3][tid] = (double)ab;
  red[4][tid] = (double)accp;
  __syncthreads();
  for (int st = BLK / 2; st > 0; st >>= 1) {
    if (tid < st) {
#pragma unroll
      for (int c = 0; c < 5; ++c) red[c][tid] += red[c][tid + st];
    }
    __syncthreads();
  }
  if (tid == 0) {
#pragma unroll
    for (int c = 0; c < 5; ++c) atomicAdd(&acc[c], red[c][0]);
  }
}

__global__ void finalize_kernel(const double* __restrict__ acc,
                                float* __restrict__ out, double inv) {
  int c = threadIdx.x;
  if (c < 5) out[c] = (float)(acc[c] * inv);
}

extern "C" void kernel_launch(void* const* d_in, const int* in_sizes, int n_in,
                              void* d_out, int out_size, void* d_ws, size_t ws_size,
                              hipStream_t stream) {
  const float* preds = (const float*)d_in[0];
  const float* targets = (const float*)d_in[1];
  int B = in_sizes[0] / (NPRED * 5);

  double* acc = (double*)d_ws;
  hipMemsetAsync(acc, 0, 5 * sizeof(double), stream);
  loss_kernel<<<B, BLK, 0, stream>>>(preds, targets, acc);
  finalize_kernel<<<1, 64, 0, stream>>>(acc, (float*)d_out,
                                        1.0 / ((double)B * NPRED));
}